// Round 3
// baseline (589.886 us; speedup 1.0000x reference)
//
#include <hip/hip_runtime.h>
#include <hip/hip_bf16.h>
#include <cmath>

// ---------------------------------------------------------------------------
// Problem constants (B=1, T=2048, D=768, H=4, N=25600, KD=128, HQ=512,
// HID_A=44, HID_S=1024, KNN=16)
// ---------------------------------------------------------------------------
#define NEG_INF (-3.402823466e38f)
#define SPLITS 32          // N-splits per head
#define SPN    800         // experts per split
#define NGRP   50          // 16-expert groups per split (even; ring depth 2)

typedef __attribute__((ext_vector_type(8))) short s16x8;   // 8 bf16 (4 VGPRs)
typedef __attribute__((ext_vector_type(4))) float f32x4;   // MFMA C/D frag

__device__ __forceinline__ unsigned short f2bf(float f) {
    union { float f; unsigned u; } v; v.f = f;
    unsigned u = v.u;
    u += 0x7fffu + ((u >> 16) & 1u);   // round-to-nearest-even
    return (unsigned short)(u >> 16);
}

// ---------------------------------------------------------------------------
// fp32 -> bf16 conversion (vectorized); keys table (large, own launch)
// ---------------------------------------------------------------------------
__global__ __launch_bounds__(256) void cvt_bf16_kernel(
        const float* __restrict__ src, unsigned short* __restrict__ dst, int n4) {
    int i = blockIdx.x * 256 + threadIdx.x;
    if (i >= n4) return;
    float4 f = ((const float4*)src)[i];
    ushort4 o;
    o.x = f2bf(f.x); o.y = f2bf(f.y); o.z = f2bf(f.z); o.w = f2bf(f.w);
    ((ushort4*)dst)[i] = o;
}

// Fused convert of {x, wq, sw1, sw3, sw2} into the contiguous bf16 region at
// ws[0 .. 8650752). Segment boundaries in float4 units.
__global__ __launch_bounds__(256) void cvt_small_kernel(
        const float* __restrict__ s0, const float* __restrict__ s1,
        const float* __restrict__ s2, const float* __restrict__ s3,
        const float* __restrict__ s4, unsigned short* __restrict__ dst) {
    int i = blockIdx.x * 256 + threadIdx.x;
    if (i >= 1081344) return;
    const float* src; int base;
    if      (i < 393216) { src = s0; base = 0; }
    else if (i < 491520) { src = s1; base = 393216; }
    else if (i < 688128) { src = s2; base = 491520; }
    else if (i < 884736) { src = s3; base = 688128; }
    else                 { src = s4; base = 884736; }
    float4 f = ((const float4*)src)[i - base];
    ushort4 o;
    o.x = f2bf(f.x); o.y = f2bf(f.y); o.z = f2bf(f.z); o.w = f2bf(f.w);
    ((ushort4*)dst)[i] = o;
}

// ---------------------------------------------------------------------------
// per-token row sum of x (fp32), one wave per token
// ---------------------------------------------------------------------------
__global__ __launch_bounds__(256) void row_sum_kernel(
        const float* __restrict__ x, float* __restrict__ sumx) {
    int gw = (blockIdx.x * 256 + threadIdx.x) >> 6;   // token id (grid sized exact)
    int lane = threadIdx.x & 63;
    const float* row = x + (size_t)gw * 768;
    float s = 0.f;
    #pragma unroll
    for (int k = 0; k < 12; ++k) s += row[lane + k * 64];
    #pragma unroll
    for (int off = 32; off > 0; off >>= 1) s += __shfl_down(s, off);
    if (lane == 0) sumx[gw] = s;
}

// ---------------------------------------------------------------------------
// GEMM  C = A @ W^T  (A: MxK bf16 row-major, W: NxK bf16 row-major)
// 64x64 tile, BK=64, 256 threads (4 waves in 2x2), 16x16x32 bf16 MFMA.
// EPI 0: q-projection epilogue (+bq, BatchNorm) -> bf16 outB
// EPI 2: final epilogue (+combsum[m]) -> fp32 outF
// ---------------------------------------------------------------------------
template <int EPI>
__global__ __launch_bounds__(256) void gemm_nt(
        const unsigned short* __restrict__ A, const unsigned short* __restrict__ W,
        int M, int N, int K,
        float* __restrict__ outF, unsigned short* __restrict__ outB,
        const float* __restrict__ p0, const float* __restrict__ p1,
        const float* __restrict__ p2, const float* __restrict__ p3,
        const float* __restrict__ p4) {
    __shared__ alignas(16) short As[64][72];   // +8 bf16 pad: 144B stride, 16B-aligned rows
    __shared__ alignas(16) short Ws[64][72];
    const int tid = threadIdx.x;
    const int m0 = blockIdx.x * 64, n0 = blockIdx.y * 64;
    const int wv = tid >> 6, lane = tid & 63;
    const int wr = wv >> 1, wc = wv & 1;
    const int lr = lane & 15, lq = lane >> 4;
    f32x4 acc[2][2];
    #pragma unroll
    for (int i = 0; i < 2; ++i)
        #pragma unroll
        for (int j = 0; j < 2; ++j) acc[i][j] = (f32x4){0.f, 0.f, 0.f, 0.f};

    for (int kb = 0; kb < K; kb += 64) {
        #pragma unroll
        for (int it = 0; it < 2; ++it) {            // 512 chunks of 8 bf16
            int chunk = tid + it * 256;
            int row = chunk >> 3, c8 = (chunk & 7) * 8;
            *(s16x8*)&As[row][c8] = *(const s16x8*)(A + (size_t)(m0 + row) * K + kb + c8);
            *(s16x8*)&Ws[row][c8] = *(const s16x8*)(W + (size_t)(n0 + row) * K + kb + c8);
        }
        __syncthreads();
        #pragma unroll
        for (int ks = 0; ks < 2; ++ks) {
            const int k0 = ks * 32 + lq * 8;
            #pragma unroll
            for (int rt = 0; rt < 2; ++rt) {
                s16x8 a = *(const s16x8*)&As[wr * 32 + rt * 16 + lr][k0];
                #pragma unroll
                for (int ct = 0; ct < 2; ++ct) {
                    s16x8 b = *(const s16x8*)&Ws[wc * 32 + ct * 16 + lr][k0];
                    acc[rt][ct] = __builtin_amdgcn_mfma_f32_16x16x32_bf16(a, b, acc[rt][ct], 0, 0, 0);
                }
            }
        }
        __syncthreads();
    }
    // C/D layout: col = lane&15, row = (lane>>4)*4 + r  [verified m89/m91]
    #pragma unroll
    for (int rt = 0; rt < 2; ++rt)
        #pragma unroll
        for (int ct = 0; ct < 2; ++ct)
            #pragma unroll
            for (int r = 0; r < 4; ++r) {
                int m = m0 + wr * 32 + rt * 16 + lq * 4 + r;
                int n = n0 + wc * 32 + ct * 16 + lr;
                float v = acc[rt][ct][r];
                if (EPI == 0) {
                    float q = v + p0[n];
                    q = (q - p3[n]) * rsqrtf(p4[n] + 1e-5f) * p1[n] + p2[n];
                    outB[(size_t)m * N + n] = f2bf(q);
                } else {
                    outF[(size_t)m * N + n] = v + p0[m];
                }
            }
}

// ---------------------------------------------------------------------------
// Dense SwiGLU up: h = silu(x@W1^T) * (x@W3^T) -> bf16, dual accumulators
// ---------------------------------------------------------------------------
__global__ __launch_bounds__(256) void gemm_swiglu_kernel(
        const unsigned short* __restrict__ A, const unsigned short* __restrict__ W1,
        const unsigned short* __restrict__ W3, int M, int N, int K,
        unsigned short* __restrict__ outB) {
    __shared__ alignas(16) short As[64][72];
    __shared__ alignas(16) short W1s[64][72];
    __shared__ alignas(16) short W3s[64][72];
    const int tid = threadIdx.x;
    const int m0 = blockIdx.x * 64, n0 = blockIdx.y * 64;
    const int wv = tid >> 6, lane = tid & 63;
    const int wr = wv >> 1, wc = wv & 1;
    const int lr = lane & 15, lq = lane >> 4;
    f32x4 acc1[2][2], acc3[2][2];
    #pragma unroll
    for (int i = 0; i < 2; ++i)
        #pragma unroll
        for (int j = 0; j < 2; ++j) {
            acc1[i][j] = (f32x4){0.f, 0.f, 0.f, 0.f};
            acc3[i][j] = (f32x4){0.f, 0.f, 0.f, 0.f};
        }
    for (int kb = 0; kb < K; kb += 64) {
        #pragma unroll
        for (int it = 0; it < 2; ++it) {
            int chunk = tid + it * 256;
            int row = chunk >> 3, c8 = (chunk & 7) * 8;
            *(s16x8*)&As[row][c8]  = *(const s16x8*)(A  + (size_t)(m0 + row) * K + kb + c8);
            *(s16x8*)&W1s[row][c8] = *(const s16x8*)(W1 + (size_t)(n0 + row) * K + kb + c8);
            *(s16x8*)&W3s[row][c8] = *(const s16x8*)(W3 + (size_t)(n0 + row) * K + kb + c8);
        }
        __syncthreads();
        #pragma unroll
        for (int ks = 0; ks < 2; ++ks) {
            const int k0 = ks * 32 + lq * 8;
            #pragma unroll
            for (int rt = 0; rt < 2; ++rt) {
                s16x8 a = *(const s16x8*)&As[wr * 32 + rt * 16 + lr][k0];
                #pragma unroll
                for (int ct = 0; ct < 2; ++ct) {
                    s16x8 b1 = *(const s16x8*)&W1s[wc * 32 + ct * 16 + lr][k0];
                    s16x8 b3 = *(const s16x8*)&W3s[wc * 32 + ct * 16 + lr][k0];
                    acc1[rt][ct] = __builtin_amdgcn_mfma_f32_16x16x32_bf16(a, b1, acc1[rt][ct], 0, 0, 0);
                    acc3[rt][ct] = __builtin_amdgcn_mfma_f32_16x16x32_bf16(a, b3, acc3[rt][ct], 0, 0, 0);
                }
            }
        }
        __syncthreads();
    }
    #pragma unroll
    for (int rt = 0; rt < 2; ++rt)
        #pragma unroll
        for (int ct = 0; ct < 2; ++ct)
            #pragma unroll
            for (int r = 0; r < 4; ++r) {
                int m = m0 + wr * 32 + rt * 16 + lq * 4 + r;
                int n = n0 + wc * 32 + ct * 16 + lr;
                float u1 = acc1[rt][ct][r], u3 = acc3[rt][ct][r];
                float hv = u1 / (1.f + expf(-u1)) * u3;
                outB[(size_t)m * N + n] = f2bf(hv);
            }
}

// ---------------------------------------------------------------------------
// Score pass kernel (both passes share the body -> bitwise-identical scores).
// A = K (experts = rows), B = Q (tokens = cols): each lane's 4 acc values
// belong to ONE token. Q register-resident (16 frags); K fragments loaded
// straight global->VGPR through a depth-2 even/odd register ring (loads for
// group g+2 issued during group g => ~2-iteration latency tolerance).
// Grid 1024 = 8 token tiles x 4 heads x 32 splits -> 4 blocks/CU; the 4
// waves of a block read IDENTICAL K data (different tokens) -> L1 reuse,
// kept phase-locked by a sync every 8 groups.
//
// PASS 1: per-(lane,token) running max over its 200 seen scores -> maxbuf
//         (128 disjoint group-maxima per (t,h): 32 splits x 4 lq-lanes).
// PASS 2: recompute scores, keep (v,idx) with v >= theta[t,h] via atomic
//         compaction (expected ~17-20 survivors, cap 64).
// ---------------------------------------------------------------------------
template <int PASS>
__global__ __launch_bounds__(256, 4) void score_pass_kernel(
        const unsigned short* __restrict__ Q,    // 2048 x 512 bf16
        const unsigned short* __restrict__ Kt,   // 4 x 25600 x 128 bf16
        float* __restrict__ maxbuf,              // [8192][128]  (pass 1 out)
        const float* __restrict__ theta,         // [8192]       (pass 2 in)
        int* __restrict__ cnt,                   // [8192]       (pass 2)
        float2* __restrict__ buf) {              // [8192][64]   (pass 2 out)
    const int b = blockIdx.x;
    const int tile = b >> 7;                     // 128 = 4 heads x 32 splits
    const int hsp = b & 127;
    const int h = hsp >> 5, sp = hsp & 31;
    const int w = threadIdx.x >> 6, lane = threadIdx.x & 63;
    const int lr = lane & 15, lq = lane >> 4;
    const int t0 = tile * 256 + w * 64;
    const unsigned short* Kh = Kt + (size_t)h * 25600 * 128;
    const int nb0 = sp * SPN;

    // Q fragments: 4 token-tiles x 4 k-steps, register-resident
    s16x8 qf[4][4];
    #pragma unroll
    for (int tt = 0; tt < 4; ++tt) {
        const unsigned short* qp = Q + (size_t)(t0 + tt * 16 + lr) * 512 + h * 128 + lq * 8;
        #pragma unroll
        for (int ks = 0; ks < 4; ++ks) qf[tt][ks] = *(const s16x8*)(qp + ks * 32);
    }

    float runmax[4] = {NEG_INF, NEG_INF, NEG_INF, NEG_INF};
    float th[4];
    if (PASS == 2) {
        #pragma unroll
        for (int tt = 0; tt < 4; ++tt) th[tt] = theta[(t0 + tt * 16 + lr) * 4 + h];
    }

    // K fragment base for this lane: row = nb0+lr, cols lq*8.. ; group stride
    // = 16 rows * 128 = 2048 elems.
    const unsigned short* kbase = Kh + (size_t)(nb0 + lr) * 128 + lq * 8;
    s16x8 kb0[4], kb1[4];
    #pragma unroll
    for (int ks = 0; ks < 4; ++ks) kb0[ks] = *(const s16x8*)(kbase + ks * 32);
    #pragma unroll
    for (int ks = 0; ks < 4; ++ks) kb1[ks] = *(const s16x8*)(kbase + 2048 + ks * 32);

    #define SCORE_GROUP(KB, GIDX)                                               \
        {                                                                       \
            f32x4 acc[4];                                                       \
            _Pragma("unroll")                                                   \
            for (int tt = 0; tt < 4; ++tt) acc[tt] = (f32x4){0.f,0.f,0.f,0.f};  \
            _Pragma("unroll")                                                   \
            for (int ks = 0; ks < 4; ++ks)                                      \
                _Pragma("unroll")                                               \
                for (int tt = 0; tt < 4; ++tt)                                  \
                    acc[tt] = __builtin_amdgcn_mfma_f32_16x16x32_bf16(          \
                        KB[ks], qf[tt][ks], acc[tt], 0, 0, 0);                  \
            /* prefetch group GIDX+2 into KB (after last read of KB) */         \
            if (GIDX + 2 < NGRP) {                                              \
                const unsigned short* kp = kbase + (size_t)(GIDX + 2) * 2048;   \
                _Pragma("unroll")                                               \
                for (int ks = 0; ks < 4; ++ks) KB[ks] = *(const s16x8*)(kp + ks * 32); \
            }                                                                   \
            if (PASS == 1) {                                                    \
                _Pragma("unroll")                                               \
                for (int tt = 0; tt < 4; ++tt) {                                \
                    float m0 = fmaxf(fmaxf(acc[tt][0], acc[tt][1]),             \
                                     fmaxf(acc[tt][2], acc[tt][3]));            \
                    runmax[tt] = fmaxf(runmax[tt], m0);                         \
                }                                                               \
            } else {                                                            \
                const int nb = nb0 + GIDX * 16;                                 \
                _Pragma("unroll")                                               \
                for (int tt = 0; tt < 4; ++tt) {                                \
                    float m0 = fmaxf(fmaxf(acc[tt][0], acc[tt][1]),             \
                                     fmaxf(acc[tt][2], acc[tt][3]));            \
                    if (m0 >= th[tt]) {                                         \
                        int g4 = (t0 + tt * 16 + lr) * 4 + h;                   \
                        _Pragma("unroll")                                       \
                        for (int r = 0; r < 4; ++r) {                           \
                            if (acc[tt][r] >= th[tt]) {                         \
                                int n = nb + lq * 4 + r;                        \
                                int pos = atomicAdd(&cnt[g4], 1);               \
                                if (pos < 64) {                                 \
                                    float2 e; e.x = acc[tt][r];                 \
                                    e.y = __int_as_float(n);                    \
                                    buf[(size_t)g4 * 64 + pos] = e;             \
                                }                                               \
                            }                                                   \
                        }                                                       \
                    }                                                           \
                }                                                               \
            }                                                                   \
        }

    for (int g2 = 0; g2 < NGRP / 2; ++g2) {
        const int ge = g2 * 2;
        SCORE_GROUP(kb0, ge)
        SCORE_GROUP(kb1, (ge + 1))
        if ((g2 & 3) == 3) __syncthreads();      // phase-lock for L1 reuse
    }
    #undef SCORE_GROUP

    if (PASS == 1) {
        #pragma unroll
        for (int tt = 0; tt < 4; ++tt)
            maxbuf[(size_t)((t0 + tt * 16 + lr) * 4 + h) * 128 + sp * 4 + lq] = runmax[tt];
    }
}

// ---------------------------------------------------------------------------
// theta = 16th-largest of the 128 group maxima per (t,h). The 128 groups
// partition all 25600 experts, so >=16 distinct experts score >= theta and
// every true top-16 score is >= theta.
// ---------------------------------------------------------------------------
__global__ __launch_bounds__(256) void theta_kernel(
        const float* __restrict__ maxbuf, float* __restrict__ theta) {
    int g = blockIdx.x * 256 + threadIdx.x;
    if (g >= 8192) return;
    const float* mb = maxbuf + (size_t)g * 128;
    float s[16];
    #pragma unroll
    for (int i = 0; i < 16; ++i) s[i] = NEG_INF;
    for (int j = 0; j < 128; ++j) {
        float v = mb[j];
        if (v > s[15]) {                 // sorted-desc shift insert
            #pragma unroll
            for (int i = 15; i > 0; --i)
                s[i] = (v > s[i - 1]) ? s[i - 1] : ((v > s[i]) ? v : s[i]);
            s[0] = (v > s[0]) ? v : s[0];
        }
    }
    theta[g] = s[15];
}

// ---------------------------------------------------------------------------
// Finalize: exact tie-aware top-16 of survivors (desc value, tie -> lower
// index, matching jax.lax.top_k), softmax gates, tiny SwiGLU 16->44->16,
// accumulate comb into per-token combsum. One thread per (token, head).
// ---------------------------------------------------------------------------
__global__ __launch_bounds__(256) void finalize_kernel(
        const int* __restrict__ cnt, const float2* __restrict__ buf,
        const float* __restrict__ sumx,
        const float* __restrict__ wdown, const float* __restrict__ wup,
        const float* __restrict__ aw1, const float* __restrict__ aw2,
        const float* __restrict__ aw3, float* __restrict__ combsum) {
    int g = blockIdx.x * 256 + threadIdx.x;    // (t*4 + h)
    if (g >= 8192) return;
    int t = g >> 2;
    int c = cnt[g]; c = (c > 64) ? 64 : c;
    float sv[16]; int si[16];
    #pragma unroll
    for (int i = 0; i < 16; ++i) { sv[i] = NEG_INF; si[i] = 0x7fffffff; }
    for (int j = 0; j < c; ++j) {
        float2 e = buf[(size_t)g * 64 + j];
        float v = e.x; int n = __float_as_int(e.y);
        bool beat = (v > sv[15]) || (v == sv[15] && n < si[15]);
        if (beat) {
            #pragma unroll
            for (int i = 15; i > 0; --i) {
                bool up  = (v > sv[i - 1]) || (v == sv[i - 1] && n < si[i - 1]);
                bool her = (v > sv[i])     || (v == sv[i]     && n < si[i]);
                float nv = up ? sv[i - 1] : (her ? v : sv[i]);
                int   ni = up ? si[i - 1] : (her ? n : si[i]);
                sv[i] = nv; si[i] = ni;
            }
            bool up0 = (v > sv[0]) || (v == sv[0] && n < si[0]);
            if (up0) { sv[0] = v; si[0] = n; }
        }
    }
    // softmax over sorted top-16 (max is sv[0])
    float mx = sv[0], den = 0.f;
    float gates[16];
    #pragma unroll
    for (int k = 0; k < 16; ++k) { gates[k] = expf(sv[k] - mx); den += gates[k]; }
    float rden = 1.f / den;
    float S = sumx[t];
    float z[16];
    #pragma unroll
    for (int k = 0; k < 16; ++k) z[k] = S * wdown[si[k]];
    float hk[16];
    #pragma unroll
    for (int k = 0; k < 16; ++k) hk[k] = 0.f;
    for (int j = 0; j < 44; ++j) {
        float u1 = 0.f, u3 = 0.f;
        #pragma unroll
        for (int k = 0; k < 16; ++k) {
            u1 += z[k] * aw1[j * 16 + k];
            u3 += z[k] * aw3[j * 16 + k];
        }
        float gj = u1 / (1.f + expf(-u1)) * u3;
        #pragma unroll
        for (int k = 0; k < 16; ++k) hk[k] += gj * aw2[k * 44 + j];
    }
    float comb = 0.f;
    #pragma unroll
    for (int k = 0; k < 16; ++k) comb += hk[k] * gates[k] * rden * wup[si[k]];
    atomicAdd(&combsum[t], comb);
}

// ---------------------------------------------------------------------------
// Host launch
// ---------------------------------------------------------------------------
extern "C" void kernel_launch(void* const* d_in, const int* in_sizes, int n_in,
                              void* d_out, int out_size, void* d_ws, size_t ws_size,
                              hipStream_t stream) {
    const float* x     = (const float*)d_in[0];
    const float* wq    = (const float*)d_in[1];
    const float* bq    = (const float*)d_in[2];
    const float* gamma = (const float*)d_in[3];
    const float* beta  = (const float*)d_in[4];
    const float* mean  = (const float*)d_in[5];
    const float* var   = (const float*)d_in[6];
    const float* keys  = (const float*)d_in[7];
    const float* wdown = (const float*)d_in[8];
    const float* wup   = (const float*)d_in[9];
    const float* aw1   = (const float*)d_in[10];
    const float* aw2   = (const float*)d_in[11];
    const float* aw3   = (const float*)d_in[12];
    const float* sw1   = (const float*)d_in[13];
    const float* sw2   = (const float*)d_in[14];
    const float* sw3   = (const float*)d_in[15];
    float* out = (float*)d_out;

    char* ws = (char*)d_ws;
    unsigned short* x_b    = (unsigned short*)(ws + 0);         // 3,145,728 B
    unsigned short* wq_b   = (unsigned short*)(ws + 3145728);   //   786,432
    unsigned short* sw1_b  = (unsigned short*)(ws + 3932160);   // 1,572,864
    unsigned short* sw3_b  = (unsigned short*)(ws + 5505024);   // 1,572,864
    unsigned short* sw2_b  = (unsigned short*)(ws + 7077888);   // 1,572,864
    unsigned short* keys_b = (unsigned short*)(ws + 8650752);   // 26,214,400
    unsigned short* q_b    = (unsigned short*)(ws + 34865152);  // 2,097,152
    float* sumx    = (float*)(ws + 36962304);                   //     8,192
    float* theta   = (float*)(ws + 36970496);                   //    32,768
    int*   cnt     = (int*)  (ws + 37003264);                   //    32,768
    float* combsum = (float*)(ws + 37036032);                   //     8,192
    // R1 region (8 MB), sequentially reused:
    //   maxbuf (8 MB, pass1 -> theta) -> buf (4 MB, pass2 -> finalize)
    //   -> h_b (4 MB, swiglu -> down-GEMM)
    char* R1 = ws + 37044224;                                   // total 45.2 MB
    float* maxbuf = (float*)R1;
    float2* buf   = (float2*)R1;
    unsigned short* h_b = (unsigned short*)R1;

    // bf16 conversions: fused small (x, wq, sw1, sw3, sw2 -> contiguous dst)
    cvt_small_kernel<<<4224, 256, 0, stream>>>(x, wq, sw1, sw3, sw2, x_b);
    cvt_bf16_kernel<<<12800, 256, 0, stream>>>(keys, keys_b, 3276800);
    row_sum_kernel<<<512, 256, 0, stream>>>(x, sumx);
    hipMemsetAsync(combsum, 0, 2048 * sizeof(float), stream);
    hipMemsetAsync(cnt, 0, 8192 * sizeof(int), stream);

    // q = BN(x @ wq^T + bq) -> bf16 (2048 x 512)
    gemm_nt<0><<<dim3(32, 8), 256, 0, stream>>>(x_b, wq_b, 2048, 512, 768,
                                                nullptr, q_b, bq, gamma, beta, mean, var);
    // pass 1: group maxima (128 per (t,h))
    score_pass_kernel<1><<<1024, 256, 0, stream>>>(q_b, keys_b, maxbuf, nullptr, nullptr, nullptr);
    // theta = 16th-largest group max
    theta_kernel<<<32, 256, 0, stream>>>(maxbuf, theta);
    // pass 2: recompute scores, compact survivors >= theta
    score_pass_kernel<2><<<1024, 256, 0, stream>>>(q_b, keys_b, nullptr, theta, cnt, buf);
    // exact top-16 + gates + tiny MLP -> combsum[t]
    finalize_kernel<<<32, 256, 0, stream>>>(cnt, buf, sumx, wdown, wup, aw1, aw2, aw3, combsum);
    // dense SwiGLU up (h bf16, 2048 x 1024)
    gemm_swiglu_kernel<<<dim3(32, 16), 256, 0, stream>>>(x_b, sw1_b, sw3_b, 2048, 1024, 768, h_b);
    // down-proj + combsum epilogue -> out fp32 (2048 x 768)
    gemm_nt<2><<<dim3(32, 12), 256, 0, stream>>>(h_b, sw2_b, 2048, 768, 1024,
                                                 out, nullptr, combsum,
                                                 nullptr, nullptr, nullptr, nullptr);
}

// Round 4
// 439.738 us; speedup vs baseline: 1.3414x; 1.3414x over previous
//
#include <hip/hip_runtime.h>
#include <hip/hip_bf16.h>
#include <cmath>

// ---------------------------------------------------------------------------
// Problem constants (B=1, T=2048, D=768, H=4, N=25600, KD=128, HQ=512,
// HID_A=44, HID_S=1024, KNN=16)
// ---------------------------------------------------------------------------
#define NEG_INF (-3.402823466e38f)
#define SPLITS 32          // N-splits per head
#define SPN    800         // experts per split
#define GRP    32          // experts per staged LDS group
#define NGRP   25          // groups per split (800/32)

typedef __attribute__((ext_vector_type(8))) short s16x8;   // 8 bf16 (4 VGPRs)
typedef __attribute__((ext_vector_type(4))) float f32x4;   // MFMA C/D frag

__device__ __forceinline__ unsigned short f2bf(float f) {
    union { float f; unsigned u; } v; v.f = f;
    unsigned u = v.u;
    u += 0x7fffu + ((u >> 16) & 1u);   // round-to-nearest-even
    return (unsigned short)(u >> 16);
}

__device__ __forceinline__ s16x8 cvt8(float4 a, float4 b) {
    s16x8 r;
    r[0] = (short)f2bf(a.x); r[1] = (short)f2bf(a.y);
    r[2] = (short)f2bf(a.z); r[3] = (short)f2bf(a.w);
    r[4] = (short)f2bf(b.x); r[5] = (short)f2bf(b.y);
    r[6] = (short)f2bf(b.z); r[7] = (short)f2bf(b.w);
    return r;
}

// ---------------------------------------------------------------------------
// Fused convert of {x, wq, sw1, sw3, sw2} into the contiguous bf16 region at
// ws[0 .. 8650752). Segment boundaries in float4 units.
// ---------------------------------------------------------------------------
__global__ __launch_bounds__(256) void cvt_small_kernel(
        const float* __restrict__ s0, const float* __restrict__ s1,
        const float* __restrict__ s2, const float* __restrict__ s3,
        const float* __restrict__ s4, unsigned short* __restrict__ dst) {
    int i = blockIdx.x * 256 + threadIdx.x;
    if (i >= 1081344) return;
    const float* src; int base;
    if      (i < 393216) { src = s0; base = 0; }
    else if (i < 491520) { src = s1; base = 393216; }
    else if (i < 688128) { src = s2; base = 491520; }
    else if (i < 884736) { src = s3; base = 688128; }
    else                 { src = s4; base = 884736; }
    float4 f = ((const float4*)src)[i - base];
    ushort4 o;
    o.x = f2bf(f.x); o.y = f2bf(f.y); o.z = f2bf(f.z); o.w = f2bf(f.w);
    ((ushort4*)dst)[i] = o;
}

// ---------------------------------------------------------------------------
// per-token row sum of x (fp32), one wave per token
// ---------------------------------------------------------------------------
__global__ __launch_bounds__(256) void row_sum_kernel(
        const float* __restrict__ x, float* __restrict__ sumx) {
    int gw = (blockIdx.x * 256 + threadIdx.x) >> 6;   // token id (grid sized exact)
    int lane = threadIdx.x & 63;
    const float* row = x + (size_t)gw * 768;
    float s = 0.f;
    #pragma unroll
    for (int k = 0; k < 12; ++k) s += row[lane + k * 64];
    #pragma unroll
    for (int off = 32; off > 0; off >>= 1) s += __shfl_down(s, off);
    if (lane == 0) sumx[gw] = s;
}

// ---------------------------------------------------------------------------
// GEMM  C = A @ W^T  (A: MxK bf16 row-major, W: NxK bf16 row-major)
// 64x64 tile, BK=64, 256 threads (4 waves in 2x2), 16x16x32 bf16 MFMA.
// EPI 0: q-projection epilogue (+bq, BatchNorm) -> bf16 outB
// EPI 2: final epilogue (+combsum[m]) -> fp32 outF
// ---------------------------------------------------------------------------
template <int EPI>
__global__ __launch_bounds__(256) void gemm_nt(
        const unsigned short* __restrict__ A, const unsigned short* __restrict__ W,
        int M, int N, int K,
        float* __restrict__ outF, unsigned short* __restrict__ outB,
        const float* __restrict__ p0, const float* __restrict__ p1,
        const float* __restrict__ p2, const float* __restrict__ p3,
        const float* __restrict__ p4) {
    __shared__ alignas(16) short As[64][72];   // +8 bf16 pad: 144B stride, 16B-aligned rows
    __shared__ alignas(16) short Ws[64][72];
    const int tid = threadIdx.x;
    const int m0 = blockIdx.x * 64, n0 = blockIdx.y * 64;
    const int wv = tid >> 6, lane = tid & 63;
    const int wr = wv >> 1, wc = wv & 1;
    const int lr = lane & 15, lq = lane >> 4;
    f32x4 acc[2][2];
    #pragma unroll
    for (int i = 0; i < 2; ++i)
        #pragma unroll
        for (int j = 0; j < 2; ++j) acc[i][j] = (f32x4){0.f, 0.f, 0.f, 0.f};

    for (int kb = 0; kb < K; kb += 64) {
        #pragma unroll
        for (int it = 0; it < 2; ++it) {            // 512 chunks of 8 bf16
            int chunk = tid + it * 256;
            int row = chunk >> 3, c8 = (chunk & 7) * 8;
            *(s16x8*)&As[row][c8] = *(const s16x8*)(A + (size_t)(m0 + row) * K + kb + c8);
            *(s16x8*)&Ws[row][c8] = *(const s16x8*)(W + (size_t)(n0 + row) * K + kb + c8);
        }
        __syncthreads();
        #pragma unroll
        for (int ks = 0; ks < 2; ++ks) {
            const int k0 = ks * 32 + lq * 8;
            #pragma unroll
            for (int rt = 0; rt < 2; ++rt) {
                s16x8 a = *(const s16x8*)&As[wr * 32 + rt * 16 + lr][k0];
                #pragma unroll
                for (int ct = 0; ct < 2; ++ct) {
                    s16x8 b = *(const s16x8*)&Ws[wc * 32 + ct * 16 + lr][k0];
                    acc[rt][ct] = __builtin_amdgcn_mfma_f32_16x16x32_bf16(a, b, acc[rt][ct], 0, 0, 0);
                }
            }
        }
        __syncthreads();
    }
    // C/D layout: col = lane&15, row = (lane>>4)*4 + r  [verified m89/m91]
    #pragma unroll
    for (int rt = 0; rt < 2; ++rt)
        #pragma unroll
        for (int ct = 0; ct < 2; ++ct)
            #pragma unroll
            for (int r = 0; r < 4; ++r) {
                int m = m0 + wr * 32 + rt * 16 + lq * 4 + r;
                int n = n0 + wc * 32 + ct * 16 + lr;
                float v = acc[rt][ct][r];
                if (EPI == 0) {
                    float q = v + p0[n];
                    q = (q - p3[n]) * rsqrtf(p4[n] + 1e-5f) * p1[n] + p2[n];
                    outB[(size_t)m * N + n] = f2bf(q);
                } else {
                    outF[(size_t)m * N + n] = v + p0[m];
                }
            }
}

// ---------------------------------------------------------------------------
// Dense SwiGLU up: h = silu(x@W1^T) * (x@W3^T) -> bf16, dual accumulators
// ---------------------------------------------------------------------------
__global__ __launch_bounds__(256) void gemm_swiglu_kernel(
        const unsigned short* __restrict__ A, const unsigned short* __restrict__ W1,
        const unsigned short* __restrict__ W3, int M, int N, int K,
        unsigned short* __restrict__ outB) {
    __shared__ alignas(16) short As[64][72];
    __shared__ alignas(16) short W1s[64][72];
    __shared__ alignas(16) short W3s[64][72];
    const int tid = threadIdx.x;
    const int m0 = blockIdx.x * 64, n0 = blockIdx.y * 64;
    const int wv = tid >> 6, lane = tid & 63;
    const int wr = wv >> 1, wc = wv & 1;
    const int lr = lane & 15, lq = lane >> 4;
    f32x4 acc1[2][2], acc3[2][2];
    #pragma unroll
    for (int i = 0; i < 2; ++i)
        #pragma unroll
        for (int j = 0; j < 2; ++j) {
            acc1[i][j] = (f32x4){0.f, 0.f, 0.f, 0.f};
            acc3[i][j] = (f32x4){0.f, 0.f, 0.f, 0.f};
        }
    for (int kb = 0; kb < K; kb += 64) {
        #pragma unroll
        for (int it = 0; it < 2; ++it) {
            int chunk = tid + it * 256;
            int row = chunk >> 3, c8 = (chunk & 7) * 8;
            *(s16x8*)&As[row][c8]  = *(const s16x8*)(A  + (size_t)(m0 + row) * K + kb + c8);
            *(s16x8*)&W1s[row][c8] = *(const s16x8*)(W1 + (size_t)(n0 + row) * K + kb + c8);
            *(s16x8*)&W3s[row][c8] = *(const s16x8*)(W3 + (size_t)(n0 + row) * K + kb + c8);
        }
        __syncthreads();
        #pragma unroll
        for (int ks = 0; ks < 2; ++ks) {
            const int k0 = ks * 32 + lq * 8;
            #pragma unroll
            for (int rt = 0; rt < 2; ++rt) {
                s16x8 a = *(const s16x8*)&As[wr * 32 + rt * 16 + lr][k0];
                #pragma unroll
                for (int ct = 0; ct < 2; ++ct) {
                    s16x8 b1 = *(const s16x8*)&W1s[wc * 32 + ct * 16 + lr][k0];
                    s16x8 b3 = *(const s16x8*)&W3s[wc * 32 + ct * 16 + lr][k0];
                    acc1[rt][ct] = __builtin_amdgcn_mfma_f32_16x16x32_bf16(a, b1, acc1[rt][ct], 0, 0, 0);
                    acc3[rt][ct] = __builtin_amdgcn_mfma_f32_16x16x32_bf16(a, b3, acc3[rt][ct], 0, 0, 0);
                }
            }
        }
        __syncthreads();
    }
    #pragma unroll
    for (int rt = 0; rt < 2; ++rt)
        #pragma unroll
        for (int ct = 0; ct < 2; ++ct)
            #pragma unroll
            for (int r = 0; r < 4; ++r) {
                int m = m0 + wr * 32 + rt * 16 + lq * 4 + r;
                int n = n0 + wc * 32 + ct * 16 + lr;
                float u1 = acc1[rt][ct][r], u3 = acc3[rt][ct][r];
                float hv = u1 / (1.f + expf(-u1)) * u3;
                outB[(size_t)m * N + n] = f2bf(hv);
            }
}

// ---------------------------------------------------------------------------
// Score pass kernel (both passes share the body -> bitwise-identical scores).
// A = K (experts = rows), B = Q (tokens = cols): each lane's 4 acc values
// belong to ONE token. Q register-resident (16 frags).
//
// Round-4 restructure (r3 was L1-miss-concurrency bound at ~6 TB/s, all
// pipes idle): K tiles are staged ONCE PER BLOCK into double-buffered LDS
// (coalesced fp32 loads, converted to bf16 in regs -> ds_write), waves read
// fragments via ds_read_b128. L1-path traffic drops 4x (819 -> 205 MB/pass)
// and the separate keys->bf16 convert kernel disappears (inline cvt, same
// f2bf rounding -> bitwise-identical scores).
//
// Grid 1024 = 8 token tiles x 4 heads x 32 splits -> 4 blocks/CU; blocks
// sharing a (h,sp) key stream are b, b+128, ... -> same XCD under b%8.
//
// PASS 1: per-(lane,token) running max -> maxbuf (128 disjoint cell-maxima
//         per (t,h): cell = (sp, lq), 25 groups x 2 subtiles x 4 rows).
// PASS 2: recompute scores, keep (v,idx) with v >= theta[t,h] via atomic
//         compaction (expected ~17-20 survivors, cap 64).
// ---------------------------------------------------------------------------
template <int PASS>
__global__ __launch_bounds__(256, 4) void score_pass_kernel(
        const unsigned short* __restrict__ Q,    // 2048 x 512 bf16
        const float* __restrict__ Kt,            // 4 x 25600 x 128 fp32
        float* __restrict__ maxbuf,              // [8192][128]  (pass 1 out)
        const float* __restrict__ theta,         // [8192]       (pass 2 in)
        int* __restrict__ cnt,                   // [8192]       (pass 2)
        float2* __restrict__ buf) {              // [8192][64]   (pass 2 out)
    __shared__ alignas(16) short Ks[2][GRP][136];   // 2 x 32 x 272B = 17.4 KB
    const int b = blockIdx.x;
    const int tile = b >> 7;                     // 128 = 4 heads x 32 splits
    const int hsp = b & 127;
    const int h = hsp >> 5, sp = hsp & 31;
    const int w = threadIdx.x >> 6, lane = threadIdx.x & 63;
    const int lr = lane & 15, lq = lane >> 4;
    const int t0 = tile * 256 + w * 64;
    const int nb0 = sp * SPN;

    // Q fragments: 4 token-tiles x 4 k-steps, register-resident (64 VGPR)
    s16x8 qf[4][4];
    #pragma unroll
    for (int tt = 0; tt < 4; ++tt) {
        const unsigned short* qp = Q + (size_t)(t0 + tt * 16 + lr) * 512 + h * 128 + lq * 8;
        #pragma unroll
        for (int ks = 0; ks < 4; ++ks) qf[tt][ks] = *(const s16x8*)(qp + ks * 32);
    }

    float runmax[4] = {NEG_INF, NEG_INF, NEG_INF, NEG_INF};
    float th[4];
    if (PASS == 2) {
        #pragma unroll
        for (int tt = 0; tt < 4; ++tt) th[tt] = theta[(t0 + tt * 16 + lr) * 4 + h];
    }

    // Staging: thread (srow, scol) covers rows srow / srow+16 of each group,
    // 8 floats (32B) each -> coalesced fp32 loads, bf16 ds_write.
    const int srow = threadIdx.x >> 4;           // 0..15
    const int scol = (threadIdx.x & 15) * 8;     // elem 0..120
    const float* kgf = Kt + ((size_t)h * 25600 + nb0 + srow) * 128 + scol;
    // group stride = GRP*128 = 4096 floats; subtile stride = 16*128 = 2048.

    {   // prologue: stage group 0 into buffer 0
        float4 a0 = ((const float4*)kgf)[0], a1 = ((const float4*)kgf)[1];
        float4 b0 = ((const float4*)(kgf + 2048))[0], b1 = ((const float4*)(kgf + 2048))[1];
        *(s16x8*)&Ks[0][srow][scol]      = cvt8(a0, a1);
        *(s16x8*)&Ks[0][srow + 16][scol] = cvt8(b0, b1);
    }

    for (int g = 0; g < NGRP; ++g) {
        // issue global loads for group g+1 (consumed after this group's MFMAs)
        float4 a0, a1, b0, b1;
        if (g + 1 < NGRP) {
            const float* kp = kgf + (size_t)(g + 1) * 4096;
            a0 = ((const float4*)kp)[0];          a1 = ((const float4*)kp)[1];
            b0 = ((const float4*)(kp + 2048))[0]; b1 = ((const float4*)(kp + 2048))[1];
        }
        __syncthreads();                          // buf[g&1] ready for all waves
        const int cb = g & 1;
        #pragma unroll
        for (int st = 0; st < 2; ++st) {          // 2 expert subtiles of 16
            f32x4 acc[4];
            #pragma unroll
            for (int tt = 0; tt < 4; ++tt) acc[tt] = (f32x4){0.f, 0.f, 0.f, 0.f};
            #pragma unroll
            for (int ks = 0; ks < 4; ++ks) {
                s16x8 ka = *(const s16x8*)&Ks[cb][st * 16 + lr][ks * 32 + lq * 8];
                #pragma unroll
                for (int tt = 0; tt < 4; ++tt)
                    acc[tt] = __builtin_amdgcn_mfma_f32_16x16x32_bf16(ka, qf[tt][ks], acc[tt], 0, 0, 0);
            }
            if (PASS == 1) {
                #pragma unroll
                for (int tt = 0; tt < 4; ++tt) {
                    float m0 = fmaxf(fmaxf(acc[tt][0], acc[tt][1]),
                                     fmaxf(acc[tt][2], acc[tt][3]));
                    runmax[tt] = fmaxf(runmax[tt], m0);
                }
            } else {
                const int nb = nb0 + g * GRP + st * 16;
                #pragma unroll
                for (int tt = 0; tt < 4; ++tt) {
                    float m0 = fmaxf(fmaxf(acc[tt][0], acc[tt][1]),
                                     fmaxf(acc[tt][2], acc[tt][3]));
                    if (m0 >= th[tt]) {
                        int g4 = (t0 + tt * 16 + lr) * 4 + h;
                        #pragma unroll
                        for (int r = 0; r < 4; ++r) {
                            if (acc[tt][r] >= th[tt]) {
                                int n = nb + lq * 4 + r;   // D row = lq*4+r
                                int pos = atomicAdd(&cnt[g4], 1);
                                if (pos < 64) {
                                    float2 e; e.x = acc[tt][r]; e.y = __int_as_float(n);
                                    buf[(size_t)g4 * 64 + pos] = e;
                                }
                            }
                        }
                    }
                }
            }
        }
        // stage group g+1 into the other buffer (vmcnt wait lands here,
        // after this group's MFMAs have issued)
        if (g + 1 < NGRP) {
            const int nbuf = cb ^ 1;
            *(s16x8*)&Ks[nbuf][srow][scol]      = cvt8(a0, a1);
            *(s16x8*)&Ks[nbuf][srow + 16][scol] = cvt8(b0, b1);
        }
    }

    if (PASS == 1) {
        #pragma unroll
        for (int tt = 0; tt < 4; ++tt)
            maxbuf[(size_t)((t0 + tt * 16 + lr) * 4 + h) * 128 + sp * 4 + lq] = runmax[tt];
    }
}

// ---------------------------------------------------------------------------
// theta = 16th-largest of the 128 cell maxima per (t,h). The 128 cells
// partition all 25600 experts, so >=16 distinct experts score >= theta and
// every true top-16 score is >= theta.
// ---------------------------------------------------------------------------
__global__ __launch_bounds__(256) void theta_kernel(
        const float* __restrict__ maxbuf, float* __restrict__ theta) {
    int g = blockIdx.x * 256 + threadIdx.x;
    if (g >= 8192) return;
    const float* mb = maxbuf + (size_t)g * 128;
    float s[16];
    #pragma unroll
    for (int i = 0; i < 16; ++i) s[i] = NEG_INF;
    for (int j = 0; j < 128; ++j) {
        float v = mb[j];
        if (v > s[15]) {                 // sorted-desc shift insert
            #pragma unroll
            for (int i = 15; i > 0; --i)
                s[i] = (v > s[i - 1]) ? s[i - 1] : ((v > s[i]) ? v : s[i]);
            s[0] = (v > s[0]) ? v : s[0];
        }
    }
    theta[g] = s[15];
}

// ---------------------------------------------------------------------------
// Finalize: exact tie-aware top-16 of survivors (desc value, tie -> lower
// index, matching jax.lax.top_k), softmax gates, tiny SwiGLU 16->44->16,
// accumulate comb into per-token combsum. One thread per (token, head).
// ---------------------------------------------------------------------------
__global__ __launch_bounds__(256) void finalize_kernel(
        const int* __restrict__ cnt, const float2* __restrict__ buf,
        const float* __restrict__ sumx,
        const float* __restrict__ wdown, const float* __restrict__ wup,
        const float* __restrict__ aw1, const float* __restrict__ aw2,
        const float* __restrict__ aw3, float* __restrict__ combsum) {
    int g = blockIdx.x * 256 + threadIdx.x;    // (t*4 + h)
    if (g >= 8192) return;
    int t = g >> 2;
    int c = cnt[g]; c = (c > 64) ? 64 : c;
    float sv[16]; int si[16];
    #pragma unroll
    for (int i = 0; i < 16; ++i) { sv[i] = NEG_INF; si[i] = 0x7fffffff; }
    for (int j = 0; j < c; ++j) {
        float2 e = buf[(size_t)g * 64 + j];
        float v = e.x; int n = __float_as_int(e.y);
        bool beat = (v > sv[15]) || (v == sv[15] && n < si[15]);
        if (beat) {
            #pragma unroll
            for (int i = 15; i > 0; --i) {
                bool up  = (v > sv[i - 1]) || (v == sv[i - 1] && n < si[i - 1]);
                bool her = (v > sv[i])     || (v == sv[i]     && n < si[i]);
                float nv = up ? sv[i - 1] : (her ? v : sv[i]);
                int   ni = up ? si[i - 1] : (her ? n : si[i]);
                sv[i] = nv; si[i] = ni;
            }
            bool up0 = (v > sv[0]) || (v == sv[0] && n < si[0]);
            if (up0) { sv[0] = v; si[0] = n; }
        }
    }
    // softmax over sorted top-16 (max is sv[0])
    float mx = sv[0], den = 0.f;
    float gates[16];
    #pragma unroll
    for (int k = 0; k < 16; ++k) { gates[k] = expf(sv[k] - mx); den += gates[k]; }
    float rden = 1.f / den;
    float S = sumx[t];
    float z[16];
    #pragma unroll
    for (int k = 0; k < 16; ++k) z[k] = S * wdown[si[k]];
    float hk[16];
    #pragma unroll
    for (int k = 0; k < 16; ++k) hk[k] = 0.f;
    for (int j = 0; j < 44; ++j) {
        float u1 = 0.f, u3 = 0.f;
        #pragma unroll
        for (int k = 0; k < 16; ++k) {
            u1 += z[k] * aw1[j * 16 + k];
            u3 += z[k] * aw3[j * 16 + k];
        }
        float gj = u1 / (1.f + expf(-u1)) * u3;
        #pragma unroll
        for (int k = 0; k < 16; ++k) hk[k] += gj * aw2[k * 44 + j];
    }
    float comb = 0.f;
    #pragma unroll
    for (int k = 0; k < 16; ++k) comb += hk[k] * gates[k] * rden * wup[si[k]];
    atomicAdd(&combsum[t], comb);
}

// ---------------------------------------------------------------------------
// Host launch
// ---------------------------------------------------------------------------
extern "C" void kernel_launch(void* const* d_in, const int* in_sizes, int n_in,
                              void* d_out, int out_size, void* d_ws, size_t ws_size,
                              hipStream_t stream) {
    const float* x     = (const float*)d_in[0];
    const float* wq    = (const float*)d_in[1];
    const float* bq    = (const float*)d_in[2];
    const float* gamma = (const float*)d_in[3];
    const float* beta  = (const float*)d_in[4];
    const float* mean  = (const float*)d_in[5];
    const float* var   = (const float*)d_in[6];
    const float* keys  = (const float*)d_in[7];
    const float* wdown = (const float*)d_in[8];
    const float* wup   = (const float*)d_in[9];
    const float* aw1   = (const float*)d_in[10];
    const float* aw2   = (const float*)d_in[11];
    const float* aw3   = (const float*)d_in[12];
    const float* sw1   = (const float*)d_in[13];
    const float* sw2   = (const float*)d_in[14];
    const float* sw3   = (const float*)d_in[15];
    float* out = (float*)d_out;

    char* ws = (char*)d_ws;
    unsigned short* x_b    = (unsigned short*)(ws + 0);         // 3,145,728 B
    unsigned short* wq_b   = (unsigned short*)(ws + 3145728);   //   786,432
    unsigned short* sw1_b  = (unsigned short*)(ws + 3932160);   // 1,572,864
    unsigned short* sw3_b  = (unsigned short*)(ws + 5505024);   // 1,572,864
    unsigned short* sw2_b  = (unsigned short*)(ws + 7077888);   // 1,572,864
    unsigned short* q_b    = (unsigned short*)(ws + 8650752);   // 2,097,152
    float* sumx    = (float*)(ws + 10747904);                   //     8,192
    float* theta   = (float*)(ws + 10756096);                   //    32,768
    float* combsum = (float*)(ws + 10788864);                   //     8,192 } one
    int*   cnt     = (int*)  (ws + 10797056);                   //    32,768 } memset
    // R1 region (4 MB), sequentially reused:
    //   maxbuf (4 MB, pass1 -> theta) -> buf (4 MB, pass2 -> finalize)
    //   -> h_b (4 MB, swiglu -> down-GEMM)
    char* R1 = ws + 10829824;                                   // total ~15 MB
    float* maxbuf = (float*)R1;
    float2* buf   = (float2*)R1;
    unsigned short* h_b = (unsigned short*)R1;

    // bf16 conversions (keys are NOT pre-converted: score_pass converts
    // inline during LDS staging with the same f2bf rounding)
    cvt_small_kernel<<<4224, 256, 0, stream>>>(x, wq, sw1, sw3, sw2, x_b);
    row_sum_kernel<<<512, 256, 0, stream>>>(x, sumx);
    hipMemsetAsync(combsum, 0, 40960, stream);   // combsum + cnt (adjacent)

    // q = BN(x @ wq^T + bq) -> bf16 (2048 x 512)
    gemm_nt<0><<<dim3(32, 8), 256, 0, stream>>>(x_b, wq_b, 2048, 512, 768,
                                                nullptr, q_b, bq, gamma, beta, mean, var);
    // pass 1: cell maxima (128 per (t,h))
    score_pass_kernel<1><<<1024, 256, 0, stream>>>(q_b, keys, maxbuf, nullptr, nullptr, nullptr);
    // theta = 16th-largest cell max
    theta_kernel<<<32, 256, 0, stream>>>(maxbuf, theta);
    // pass 2: recompute scores, compact survivors >= theta
    score_pass_kernel<2><<<1024, 256, 0, stream>>>(q_b, keys, nullptr, theta, cnt, buf);
    // exact top-16 + gates + tiny MLP -> combsum[t]
    finalize_kernel<<<32, 256, 0, stream>>>(cnt, buf, sumx, wdown, wup, aw1, aw2, aw3, combsum);
    // dense SwiGLU up (h bf16, 2048 x 1024)
    gemm_swiglu_kernel<<<dim3(32, 16), 256, 0, stream>>>(x_b, sw1_b, sw3_b, 2048, 1024, 768, h_b);
    // down-proj + combsum epilogue -> out fp32 (2048 x 768)
    gemm_nt<2><<<dim3(32, 12), 256, 0, stream>>>(h_b, sw2_b, 2048, 768, 1024,
                                                 out, nullptr, combsum,
                                                 nullptr, nullptr, nullptr, nullptr);
}